// Round 8
// baseline (31.296 us; speedup 1.0000x reference)
//
#include <hip/hip_runtime.h>
#include <math.h>

// B=4096, O=8, E=64, I=4, V=3, P=perm(8,3)=336
// unary_feats  (B,8,64)   f32
// binary_feats (B,8,8,64) f32
// rule_unary   (4,3,64)   f32  = [12][64]
// rule_binary  (4,3,3,64) f32  = [36][64]
// out          (B,4)      f32  (col0=sel0+sel1, col1=sel2+sel3, col2=col3=0)
//
// v8: pair-table-direct MFMA. score(i;a,b,c) =
//   Q01r[a][b] + Q02r[a][c] + Q12r[b][c] + s0[a] + s1[b] + s2[c]
// where Qxy r[x][y] = dot(concat(bf[x,y],bf[y,x]), concat(rb_nm, rb_mn))
// (one M=64 N=16 K=128 GEMM, 4 MFMA/wave) and s_n[v] = um_n[v] + bm_nn[v,v]
// (two accumulated 16x16x64 GEMMs on wave 3). No bm_t intermediate, no
// phase-2 pass. LDS ~4.9 KB. Rules pre-packed once into ws as bf16 B-frags.

typedef __attribute__((ext_vector_type(8))) __bf16 bf16x8;
typedef __attribute__((ext_vector_type(4))) float  f32x4;

#define QS 68   // q_s row stride (floats)
#define SS 12   // s_s row stride (floats)

__device__ inline bf16x8 cvt2(const float4 v0, const float4 v1) {
    bf16x8 r;
    r[0] = (__bf16)v0.x; r[1] = (__bf16)v0.y; r[2] = (__bf16)v0.z; r[3] = (__bf16)v0.w;
    r[4] = (__bf16)v1.x; r[5] = (__bf16)v1.y; r[6] = (__bf16)v1.z; r[7] = (__bf16)v1.w;
    return r;
}

// ---- prep: pack R2 / diag / unary rule B-fragments (bf16) into ws ----
// bf16 idx: [0,2048)   R2 frags  [s=0..3][lane][e8], R2[col][k]:
//             col=i*3+t; k<64: rb[i][n1][m1][k], k>=64: rb[i][n2][m2][k-64]
//             t=0:(0,1)/(1,0)  t=1:(0,2)/(2,0)  t=2:(1,2)/(2,1)
// [2048,3072) diag frags [s=0..1][lane][e8]: rb[i][n][n][k], col=i*3+n
// [3072,4096) unary frags[s=0..1][lane][e8]: ru[col][k]
__global__ __launch_bounds__(256) void rule_prep_kernel(
    const float* __restrict__ ru, const float* __restrict__ rb,
    __bf16* __restrict__ wsb)
{
    const int idx = blockIdx.x * 256 + threadIdx.x;
    if (idx >= 4096) return;
    const int lane = (idx >> 3) & 63;
    const int e    = idx & 7;
    const int col  = lane & 15;
    const int kg   = lane >> 4;
    float val = 0.f;
    if (idx < 2048) {
        const int s = idx >> 9;
        const int k = s * 32 + kg * 8 + e;
        if (col < 12) {
            const int i = col / 3, t = col % 3;
            int n, m, kk;
            if (k < 64) { kk = k;      n = (t == 2) ? 1 : 0; m = (t == 0) ? 1 : 2; }
            else        { kk = k - 64; n = (t == 0) ? 1 : 2; m = (t == 2) ? 1 : 0; }
            val = rb[((i * 3 + n) * 3 + m) * 64 + kk];
        }
    } else if (idx < 3072) {
        const int s = (idx - 2048) >> 9;
        const int k = s * 32 + kg * 8 + e;
        if (col < 12) {
            const int i = col / 3, n = col % 3;
            val = rb[((i * 3 + n) * 3 + n) * 64 + k];
        }
    } else {
        const int s = (idx - 3072) >> 9;
        const int k = s * 32 + kg * 8 + e;
        if (col < 12) val = ru[col * 64 + k];
    }
    wsb[idx] = (__bf16)val;
}

__global__ __launch_bounds__(256) void rule_learner_kernel(
    const float* __restrict__ uf,    // (B,8,64)
    const float* __restrict__ bfe,   // (B,8,8,64)
    const bf16x8* __restrict__ wsb,  // packed rule fragments
    float* __restrict__ out)         // (B,4)
{
    const int b     = blockIdx.x;
    const int tid   = threadIdx.x;
    const int lane  = tid & 63;
    const int w     = tid >> 6;      // wave id = pair strip = rule set (phase 3)
    const int row16 = lane & 15;
    const int kg    = lane >> 4;
    const int kb    = kg * 8;

    __shared__ float q_s[16 * QS];   // 4352 B: [col=i*3+t][pair=x*8+y]
    __shared__ float s_s[12 * SS];   // 576 B:  [col=i*3+n][v]
    __shared__ float wmin[4];

    // ---- binary pair GEMM: C[pair][col], K=128 (two feature rows) ----
    {
        const float* base = bfe + (size_t)b * 4096;
        const int p  = w * 16 + row16;          // pair index (x,y)
        const int x  = p >> 3, y = p & 7;
        const float* rA = base + (x * 8 + y) * 64 + kb;   // k 0..63
        const float* rB = base + (y * 8 + x) * 64 + kb;   // k 64..127
        const bf16x8 a0 = cvt2(*(const float4*)rA,        *(const float4*)(rA + 4));
        const bf16x8 a1 = cvt2(*(const float4*)(rA + 32), *(const float4*)(rA + 36));
        const bf16x8 a2 = cvt2(*(const float4*)rB,        *(const float4*)(rB + 4));
        const bf16x8 a3 = cvt2(*(const float4*)(rB + 32), *(const float4*)(rB + 36));
        f32x4 acc = {0.f, 0.f, 0.f, 0.f};
        acc = __builtin_amdgcn_mfma_f32_16x16x32_bf16(a0, wsb[0 * 64 + lane], acc, 0, 0, 0);
        acc = __builtin_amdgcn_mfma_f32_16x16x32_bf16(a1, wsb[1 * 64 + lane], acc, 0, 0, 0);
        acc = __builtin_amdgcn_mfma_f32_16x16x32_bf16(a2, wsb[2 * 64 + lane], acc, 0, 0, 0);
        acc = __builtin_amdgcn_mfma_f32_16x16x32_bf16(a3, wsb[3 * 64 + lane], acc, 0, 0, 0);
        // C: col = lane&15 (rule col), rows = pairs w*16 + kg*4 + t
        *(float4*)&q_s[row16 * QS + w * 16 + kg * 4] = *(float4*)&acc;
    }

    // ---- separable terms (wave 3): s_n[i][v] = um_n[v] + bm_nn[v,v] ----
    if (w == 3) {
        const int v = row16 < 8 ? row16 : 7;    // clamp M-pad rows (outputs unused)
        const float* base = bfe + (size_t)b * 4096;
        const float* dA = base + v * 576 + kb;          // bf[v][v][:]
        const float* uA = uf + (size_t)b * 512 + v * 64 + kb;
        const bf16x8 ua0 = cvt2(*(const float4*)uA,        *(const float4*)(uA + 4));
        const bf16x8 ua1 = cvt2(*(const float4*)(uA + 32), *(const float4*)(uA + 36));
        const bf16x8 da0 = cvt2(*(const float4*)dA,        *(const float4*)(dA + 4));
        const bf16x8 da1 = cvt2(*(const float4*)(dA + 32), *(const float4*)(dA + 36));
        f32x4 acc = {0.f, 0.f, 0.f, 0.f};
        acc = __builtin_amdgcn_mfma_f32_16x16x32_bf16(ua0, wsb[384 + lane], acc, 0, 0, 0);
        acc = __builtin_amdgcn_mfma_f32_16x16x32_bf16(ua1, wsb[448 + lane], acc, 0, 0, 0);
        acc = __builtin_amdgcn_mfma_f32_16x16x32_bf16(da0, wsb[256 + lane], acc, 0, 0, 0);
        acc = __builtin_amdgcn_mfma_f32_16x16x32_bf16(da1, wsb[320 + lane], acc, 0, 0, 0);
        if (row16 < 12 && kg < 2)               // objects v = kg*4+t in kg 0,1
            *(float4*)&s_s[row16 * SS + kg * 4] = *(float4*)&acc;
    }
    __syncthreads();   // B1: q_s / s_s readable

    // ---- phase 3 (wave-local i=w): lane = ordered pair (a,bb), sweep cc ----
    float mn = INFINITY;
    if (lane < 56) {
        const int a  = lane / 7;
        const int o  = lane - a * 7;
        const int bb = o + (o >= a);
        const float* q1 = &q_s[(w * 3 + 0) * QS];
        const float* q2 = &q_s[(w * 3 + 1) * QS];
        const float* q3 = &q_s[(w * 3 + 2) * QS];
        const float bs = q1[a * 8 + bb] + s_s[(w * 3 + 0) * SS + a]
                                        + s_s[(w * 3 + 1) * SS + bb];
        const float4 c0 = *(const float4*)&q2[a * 8];
        const float4 c1 = *(const float4*)&q2[a * 8 + 4];
        const float4 d0 = *(const float4*)&q3[bb * 8];
        const float4 d1 = *(const float4*)&q3[bb * 8 + 4];
        const float4 e0 = *(const float4*)&s_s[(w * 3 + 2) * SS];      // uniform
        const float4 e1 = *(const float4*)&s_s[(w * 3 + 2) * SS + 4];  // broadcast
        float vv[8];
        vv[0] = c0.x + d0.x + e0.x; vv[1] = c0.y + d0.y + e0.y;
        vv[2] = c0.z + d0.z + e0.z; vv[3] = c0.w + d0.w + e0.w;
        vv[4] = c1.x + d1.x + e1.x; vv[5] = c1.y + d1.y + e1.y;
        vv[6] = c1.z + d1.z + e1.z; vv[7] = c1.w + d1.w + e1.w;
        #pragma unroll
        for (int cc = 0; cc < 8; ++cc) {
            const float s = (cc == a || cc == bb) ? INFINITY : (bs + vv[cc]);
            mn = fminf(mn, s);
        }
    }

    mn = fminf(mn, __shfl_xor(mn, 1));
    mn = fminf(mn, __shfl_xor(mn, 2));
    mn = fminf(mn, __shfl_xor(mn, 4));
    mn = fminf(mn, __shfl_xor(mn, 8));
    mn = fminf(mn, __shfl_xor(mn, 16));
    mn = fminf(mn, __shfl_xor(mn, 32));
    if (lane == 0) wmin[w] = mn;
    __syncthreads();   // B2: wmin ready

    if (tid == 0) {
        const float m0 = wmin[0], m1 = wmin[1], m2 = wmin[2], m3 = wmin[3];
        const float mx = fmaxf(fmaxf(m0, m1), fmaxf(m2, m3));
        const float e0 = expf(m0 - mx), e1 = expf(m1 - mx);
        const float e2 = expf(m2 - mx), e3 = expf(m3 - mx);
        const float inv = 1.f / (e0 + e1 + e2 + e3);
        *(float4*)(out + (size_t)b * 4) =
            make_float4((e0 + e1) * inv, (e2 + e3) * inv, 0.f, 0.f);
    }
}

extern "C" void kernel_launch(void* const* d_in, const int* in_sizes, int n_in,
                              void* d_out, int out_size, void* d_ws, size_t ws_size,
                              hipStream_t stream) {
    const float* uf = (const float*)d_in[0];   // (4096,8,64)
    const float* bf = (const float*)d_in[1];   // (4096,8,8,64)
    const float* ru = (const float*)d_in[2];   // (4,3,64)
    const float* rb = (const float*)d_in[3];   // (4,3,3,64)
    float* out = (float*)d_out;                // (4096,4)

    const int B = in_sizes[0] / (8 * 64);      // 4096

    rule_prep_kernel<<<16, 256, 0, stream>>>(ru, rb, (__bf16*)d_ws);
    rule_learner_kernel<<<B, 256, 0, stream>>>(uf, bf, (const bf16x8*)d_ws, out);
}

// Round 9
// 27.162 us; speedup vs baseline: 1.1522x; 1.1522x over previous
//
#include <hip/hip_runtime.h>
#include <math.h>

// B=4096, O=8, E=64, I=4, V=3, P=perm(8,3)=336
// unary_feats  (B,8,64)   f32
// binary_feats (B,8,8,64) f32
// rule_unary   (4,3,64)   f32  = [12][64]
// rule_binary  (4,3,3,64) f32  = [36][64]  (rule = i*9 + n*3 + m)
// out          (B,4)      f32  (col0=sel0+sel1, col1=sel2+sel3, col2=col3=0)
//
// v9: wave-autonomous. 1 wave == 1 batch element, 64-thread workgroups,
// wave-private LDS, ZERO __syncthreads. Binary match = in-wave 64x36x64
// GEMM (4 pos-tiles x 3 rule-tiles x 2 K-halves = 24 MFMA) + unary 2 MFMA,
// rules pre-packed once into ws as bf16 B-fragments (v5 prep, R6 lesson:
// packed beats re-converting per block). bm[rule][pos] -> q-tables
// (q01/q02/q12 per rule-set) -> 56-pair sweep, 4-wide butterfly min,
// lane0 softmax. In-wave LDS ordering via compiler lgkmcnt (no barriers).

typedef __attribute__((ext_vector_type(8))) __bf16 bf16x8;
typedef __attribute__((ext_vector_type(4))) float  f32x4;

#define BMS 68   // bm row stride (floats): uniform 8-lane b128 slots, aligned
#define QS3 68   // q row stride

__device__ inline bf16x8 cvt2(const float4 v0, const float4 v1) {
    bf16x8 r;
    r[0] = (__bf16)v0.x; r[1] = (__bf16)v0.y; r[2] = (__bf16)v0.z; r[3] = (__bf16)v0.w;
    r[4] = (__bf16)v1.x; r[5] = (__bf16)v1.y; r[6] = (__bf16)v1.z; r[7] = (__bf16)v1.w;
    return r;
}

// ---- prep: pack rules as bf16 MFMA B-fragments into ws (once) ----
// bf16 layout: [nt(3)][h(2)][lane(64)][e(8)] then unary [h(2)][lane(64)][e(8)]
// B-frag: col = lane&15 (rule nt*16+col / ruleu col), k = h*32 + (lane>>4)*8 + e
__global__ __launch_bounds__(256) void rule_prep_kernel(
    const float* __restrict__ ru, const float* __restrict__ rb,
    __bf16* __restrict__ wsb)
{
    const int idx = blockIdx.x * 256 + threadIdx.x;
    if (idx >= 4096) return;
    const int lane = (idx >> 3) & 63;
    const int e    = idx & 7;
    float val;
    if (idx < 3072) {
        const int nt   = idx >> 10;
        const int h    = (idx >> 9) & 1;
        const int rule = nt * 16 + (lane & 15);
        const int k    = h * 32 + (lane >> 4) * 8 + e;
        val = (rule < 36) ? rb[rule * 64 + k] : 0.f;
    } else {
        const int u    = idx - 3072;
        const int h    = u >> 9;
        const int ru16 = lane & 15;
        const int k    = h * 32 + (lane >> 4) * 8 + e;
        val = (ru16 < 12) ? ru[ru16 * 64 + k] : 0.f;
    }
    wsb[idx] = (__bf16)val;
}

__global__ __launch_bounds__(64) void rule_learner_kernel(
    const float* __restrict__ uf,    // (B,8,64)
    const float* __restrict__ bfe,   // (B,8,8,64)
    const bf16x8* __restrict__ wsb,  // packed rule fragments
    float* __restrict__ out)         // (B,4)
{
    const int b     = blockIdx.x;
    const int lane  = threadIdx.x;   // one wave per block
    const int row16 = lane & 15;
    const int kg    = lane >> 4;
    const int kb    = kg * 8;

    __shared__ float bm[36 * BMS];   // 9792 B  [rule][pos]
    __shared__ float um[12 * 12];    // 576 B   [i*3+n][v]
    __shared__ float q [12 * QS3];   // 3264 B  [i*3+t][pair]  t:0=q01 1=q02 2=q12

    // ---- issue ALL global loads up front (fill the memory pipe) ----
    const float* base = bfe + (size_t)b * 4096;
    float4 af[4][4];
    #pragma unroll
    for (int t = 0; t < 4; ++t) {
        const float* rp = base + (size_t)(t * 16 + row16) * 64 + kb;
        af[t][0] = *(const float4*)rp;
        af[t][1] = *(const float4*)(rp + 4);
        af[t][2] = *(const float4*)(rp + 32);
        af[t][3] = *(const float4*)(rp + 36);
    }
    float4 uA[4];
    {
        const float* up = uf + (size_t)b * 512 + (row16 < 8 ? row16 : 7) * 64 + kb;
        uA[0] = *(const float4*)up;
        uA[1] = *(const float4*)(up + 4);
        uA[2] = *(const float4*)(up + 32);
        uA[3] = *(const float4*)(up + 36);
    }
    bf16x8 rbf[6];
    #pragma unroll
    for (int t = 0; t < 6; ++t) rbf[t] = wsb[t * 64 + lane];
    const bf16x8 ruf0 = wsb[384 + lane];
    const bf16x8 ruf1 = wsb[448 + lane];

    // ---- binary match GEMM: bm[rule][pos], 4 pos-tiles x 3 rule-tiles ----
    #pragma unroll
    for (int t = 0; t < 4; ++t) {
        const bf16x8 a0 = cvt2(af[t][0], af[t][1]);   // k 0..31 (kg-sliced)
        const bf16x8 a1 = cvt2(af[t][2], af[t][3]);   // k 32..63
        #pragma unroll
        for (int nt = 0; nt < 3; ++nt) {
            f32x4 acc = {0.f, 0.f, 0.f, 0.f};
            acc = __builtin_amdgcn_mfma_f32_16x16x32_bf16(a0, rbf[nt * 2 + 0], acc, 0, 0, 0);
            acc = __builtin_amdgcn_mfma_f32_16x16x32_bf16(a1, rbf[nt * 2 + 1], acc, 0, 0, 0);
            // C: col = lane&15 (rule), rows = kg*4 + reg (pos within tile)
            const int rule = nt * 16 + row16;
            if (rule < 36)
                *(float4*)&bm[rule * BMS + t * 16 + kg * 4] = *(float4*)&acc;
        }
    }
    // ---- unary match: um[i*3+n][v] (+M-pad clamp; garbage rows never read) ----
    {
        const bf16x8 ua0 = cvt2(uA[0], uA[1]);
        const bf16x8 ua1 = cvt2(uA[2], uA[3]);
        f32x4 acc = {0.f, 0.f, 0.f, 0.f};
        acc = __builtin_amdgcn_mfma_f32_16x16x32_bf16(ua0, ruf0, acc, 0, 0, 0);
        acc = __builtin_amdgcn_mfma_f32_16x16x32_bf16(ua1, ruf1, acc, 0, 0, 0);
        if (row16 < 12 && kg < 2)
            *(float4*)&um[row16 * 12 + kg * 4] = *(float4*)&acc;
    }

    // ---- phase 2: q-tables for all 4 rule-sets (lane = pair (x,y)) ----
    {
        const int x = lane >> 3;
        const int y = lane & 7;
        #pragma unroll
        for (int i = 0; i < 4; ++i) {
            const float* bmi = bm + i * 9 * BMS;
            const float* umi = um + i * 3 * 12;
            const float q01 = umi[x] + umi[12 + y]
                            + bmi[0 * BMS + x * 9] + bmi[4 * BMS + y * 9]
                            + bmi[1 * BMS + x * 8 + y] + bmi[3 * BMS + y * 8 + x];
            const float q02 = umi[24 + y] + bmi[8 * BMS + y * 9]
                            + bmi[2 * BMS + x * 8 + y] + bmi[6 * BMS + y * 8 + x];
            const float q12 = bmi[5 * BMS + x * 8 + y] + bmi[7 * BMS + y * 8 + x];
            q[(i * 3 + 0) * QS3 + lane] = q01;
            q[(i * 3 + 1) * QS3 + lane] = q02;
            q[(i * 3 + 2) * QS3 + lane] = q12;
        }
    }

    // ---- phase 3: lane = ordered pair (a,bb), sweep cc for all 4 i ----
    float mn[4] = {INFINITY, INFINITY, INFINITY, INFINITY};
    if (lane < 56) {
        const int a  = lane / 7;
        const int o  = lane - a * 7;
        const int bb = o + (o >= a);
        #pragma unroll
        for (int i = 0; i < 4; ++i) {
            const float bs  = q[(i * 3 + 0) * QS3 + a * 8 + bb];
            const float4 c0 = *(const float4*)&q[(i * 3 + 1) * QS3 + a * 8];
            const float4 c1 = *(const float4*)&q[(i * 3 + 1) * QS3 + a * 8 + 4];
            const float4 d0 = *(const float4*)&q[(i * 3 + 2) * QS3 + bb * 8];
            const float4 d1 = *(const float4*)&q[(i * 3 + 2) * QS3 + bb * 8 + 4];
            float vv[8];
            vv[0] = c0.x + d0.x; vv[1] = c0.y + d0.y;
            vv[2] = c0.z + d0.z; vv[3] = c0.w + d0.w;
            vv[4] = c1.x + d1.x; vv[5] = c1.y + d1.y;
            vv[6] = c1.z + d1.z; vv[7] = c1.w + d1.w;
            float m = INFINITY;
            #pragma unroll
            for (int cc = 0; cc < 8; ++cc) {
                const float s = (cc == a || cc == bb) ? INFINITY : (bs + vv[cc]);
                m = fminf(m, s);
            }
            mn[i] = m;
        }
    }
    #pragma unroll
    for (int s = 1; s <= 32; s <<= 1) {
        #pragma unroll
        for (int i = 0; i < 4; ++i) mn[i] = fminf(mn[i], __shfl_xor(mn[i], s));
    }

    if (lane == 0) {
        const float mx = fmaxf(fmaxf(mn[0], mn[1]), fmaxf(mn[2], mn[3]));
        const float e0 = expf(mn[0] - mx), e1 = expf(mn[1] - mx);
        const float e2 = expf(mn[2] - mx), e3 = expf(mn[3] - mx);
        const float inv = 1.f / (e0 + e1 + e2 + e3);
        *(float4*)(out + (size_t)b * 4) =
            make_float4((e0 + e1) * inv, (e2 + e3) * inv, 0.f, 0.f);
    }
}

extern "C" void kernel_launch(void* const* d_in, const int* in_sizes, int n_in,
                              void* d_out, int out_size, void* d_ws, size_t ws_size,
                              hipStream_t stream) {
    const float* uf = (const float*)d_in[0];   // (4096,8,64)
    const float* bf = (const float*)d_in[1];   // (4096,8,8,64)
    const float* ru = (const float*)d_in[2];   // (4,3,64)
    const float* rb = (const float*)d_in[3];   // (4,3,3,64)
    float* out = (float*)d_out;                // (4096,4)

    const int B = in_sizes[0] / (8 * 64);      // 4096

    rule_prep_kernel<<<16, 256, 0, stream>>>(ru, rb, (__bf16*)d_ws);
    rule_learner_kernel<<<B, 64, 0, stream>>>(uf, bf, (const bf16x8*)d_ws, out);
}

// Round 10
// 24.336 us; speedup vs baseline: 1.2860x; 1.1162x over previous
//
#include <hip/hip_runtime.h>
#include <math.h>

// B=4096, O=8, E=64, I=4, V=3, P=perm(8,3)=336
// unary_feats  (B,8,64)   f32
// binary_feats (B,8,8,64) f32
// rule_unary   (4,3,64)   f32  = [12][64]
// rule_binary  (4,3,3,64) f32  = [36][64]  (rule = i*9 + n*3 + m)
// out          (B,4)      f32  (col0=sel0+sel1, col1=sel2+sel3, col2=col3=0)
//
// v10 = v9 (wave-autonomous, zero block barriers) + 2 elements per wave:
// grid 2048 -> 8 blocks/CU needed, 11 resident (13.6KB LDS) -> whole grid
// co-resident, no sequential rounds. Elem1's global loads issue before
// elem0's LDS phases (latency hidden). LDS reuse across elements guarded by
// lgkmcnt(0)+sched_barrier only (no vmcnt drain; in-wave DS ordering
// validated by v9). Rules pre-packed once into ws as bf16 B-fragments.

typedef __attribute__((ext_vector_type(8))) __bf16 bf16x8;
typedef __attribute__((ext_vector_type(4))) float  f32x4;

#define BMS 68
#define QS3 68

__device__ inline bf16x8 cvt2(const float4 v0, const float4 v1) {
    bf16x8 r;
    r[0] = (__bf16)v0.x; r[1] = (__bf16)v0.y; r[2] = (__bf16)v0.z; r[3] = (__bf16)v0.w;
    r[4] = (__bf16)v1.x; r[5] = (__bf16)v1.y; r[6] = (__bf16)v1.z; r[7] = (__bf16)v1.w;
    return r;
}

// ---- prep: pack rules as bf16 MFMA B-fragments into ws (once) ----
// bf16 layout: [nt(3)][h(2)][lane(64)][e(8)] then unary [h(2)][lane(64)][e(8)]
__global__ __launch_bounds__(256) void rule_prep_kernel(
    const float* __restrict__ ru, const float* __restrict__ rb,
    __bf16* __restrict__ wsb)
{
    const int idx = blockIdx.x * 256 + threadIdx.x;
    if (idx >= 4096) return;
    const int lane = (idx >> 3) & 63;
    const int e    = idx & 7;
    float val;
    if (idx < 3072) {
        const int nt   = idx >> 10;
        const int h    = (idx >> 9) & 1;
        const int rule = nt * 16 + (lane & 15);
        const int k    = h * 32 + (lane >> 4) * 8 + e;
        val = (rule < 36) ? rb[rule * 64 + k] : 0.f;
    } else {
        const int u    = idx - 3072;
        const int h    = u >> 9;
        const int ru16 = lane & 15;
        const int k    = h * 32 + (lane >> 4) * 8 + e;
        val = (ru16 < 12) ? ru[ru16 * 64 + k] : 0.f;
    }
    wsb[idx] = (__bf16)val;
}

__global__ __launch_bounds__(64, 2) void rule_learner_kernel(
    const float* __restrict__ uf,    // (B,8,64)
    const float* __restrict__ bfe,   // (B,8,8,64)
    const bf16x8* __restrict__ wsb,  // packed rule fragments
    float* __restrict__ out)         // (B,4)
{
    const int b0    = blockIdx.x * 2;
    const int lane  = threadIdx.x;   // one wave per block
    const int row16 = lane & 15;
    const int kg    = lane >> 4;
    const int kb    = kg * 8;

    __shared__ float bm[36 * BMS];   // 9792 B  [rule][pos]
    __shared__ float um[12 * 12];    // 576 B   [i*3+n][v]
    __shared__ float q [12 * QS3];   // 3264 B  [i*3+t][pair]

    // ---- rule fragments (L2-hot, contiguous) ----
    bf16x8 rbf[6];
    #pragma unroll
    for (int t = 0; t < 6; ++t) rbf[t] = wsb[t * 64 + lane];
    const bf16x8 ruf0 = wsb[384 + lane];
    const bf16x8 ruf1 = wsb[448 + lane];

    // ---- elem0 loads ----
    float4 af[4][4], uA[4];
    {
        const float* base = bfe + (size_t)b0 * 4096;
        #pragma unroll
        for (int t = 0; t < 4; ++t) {
            const float* rp = base + (size_t)(t * 16 + row16) * 64 + kb;
            af[t][0] = *(const float4*)rp;
            af[t][1] = *(const float4*)(rp + 4);
            af[t][2] = *(const float4*)(rp + 32);
            af[t][3] = *(const float4*)(rp + 36);
        }
        const float* up = uf + (size_t)b0 * 512 + (row16 < 8 ? row16 : 7) * 64 + kb;
        uA[0] = *(const float4*)up;
        uA[1] = *(const float4*)(up + 4);
        uA[2] = *(const float4*)(up + 32);
        uA[3] = *(const float4*)(up + 36);
    }

    #pragma unroll
    for (int e = 0; e < 2; ++e) {
        // ---- phase 1: MFMA matches into bm/um ----
        #pragma unroll
        for (int t = 0; t < 4; ++t) {
            const bf16x8 a0 = cvt2(af[t][0], af[t][1]);
            const bf16x8 a1 = cvt2(af[t][2], af[t][3]);
            #pragma unroll
            for (int nt = 0; nt < 3; ++nt) {
                f32x4 acc = {0.f, 0.f, 0.f, 0.f};
                acc = __builtin_amdgcn_mfma_f32_16x16x32_bf16(a0, rbf[nt * 2 + 0], acc, 0, 0, 0);
                acc = __builtin_amdgcn_mfma_f32_16x16x32_bf16(a1, rbf[nt * 2 + 1], acc, 0, 0, 0);
                const int rule = nt * 16 + row16;
                if (rule < 36)
                    *(float4*)&bm[rule * BMS + t * 16 + kg * 4] = *(float4*)&acc;
            }
        }
        {
            const bf16x8 ua0 = cvt2(uA[0], uA[1]);
            const bf16x8 ua1 = cvt2(uA[2], uA[3]);
            f32x4 acc = {0.f, 0.f, 0.f, 0.f};
            acc = __builtin_amdgcn_mfma_f32_16x16x32_bf16(ua0, ruf0, acc, 0, 0, 0);
            acc = __builtin_amdgcn_mfma_f32_16x16x32_bf16(ua1, ruf1, acc, 0, 0, 0);
            if (row16 < 12 && kg < 2)
                *(float4*)&um[row16 * 12 + kg * 4] = *(float4*)&acc;
        }

        // ---- issue elem1 loads NOW (latency hides under phases 2-3) ----
        if (e == 0) {
            const float* base = bfe + (size_t)(b0 + 1) * 4096;
            #pragma unroll
            for (int t = 0; t < 4; ++t) {
                const float* rp = base + (size_t)(t * 16 + row16) * 64 + kb;
                af[t][0] = *(const float4*)rp;
                af[t][1] = *(const float4*)(rp + 4);
                af[t][2] = *(const float4*)(rp + 32);
                af[t][3] = *(const float4*)(rp + 36);
            }
            const float* up = uf + (size_t)(b0 + 1) * 512
                            + (row16 < 8 ? row16 : 7) * 64 + kb;
            uA[0] = *(const float4*)up;
            uA[1] = *(const float4*)(up + 4);
            uA[2] = *(const float4*)(up + 32);
            uA[3] = *(const float4*)(up + 36);
        }

        // ---- phase 2: q-tables for all 4 rule-sets (lane = pair (x,y)) ----
        {
            const int x = lane >> 3;
            const int y = lane & 7;
            #pragma unroll
            for (int i = 0; i < 4; ++i) {
                const float* bmi = bm + i * 9 * BMS;
                const float* umi = um + i * 3 * 12;
                const float q01 = umi[x] + umi[12 + y]
                                + bmi[0 * BMS + x * 9] + bmi[4 * BMS + y * 9]
                                + bmi[1 * BMS + x * 8 + y] + bmi[3 * BMS + y * 8 + x];
                const float q02 = umi[24 + y] + bmi[8 * BMS + y * 9]
                                + bmi[2 * BMS + x * 8 + y] + bmi[6 * BMS + y * 8 + x];
                const float q12 = bmi[5 * BMS + x * 8 + y] + bmi[7 * BMS + y * 8 + x];
                q[(i * 3 + 0) * QS3 + lane] = q01;
                q[(i * 3 + 1) * QS3 + lane] = q02;
                q[(i * 3 + 2) * QS3 + lane] = q12;
            }
        }

        // ---- phase 3: lane = ordered pair (a,bb), sweep cc for all 4 i ----
        float mn[4] = {INFINITY, INFINITY, INFINITY, INFINITY};
        if (lane < 56) {
            const int a  = lane / 7;
            const int o  = lane - a * 7;
            const int bb = o + (o >= a);
            #pragma unroll
            for (int i = 0; i < 4; ++i) {
                const float bs  = q[(i * 3 + 0) * QS3 + a * 8 + bb];
                const float4 c0 = *(const float4*)&q[(i * 3 + 1) * QS3 + a * 8];
                const float4 c1 = *(const float4*)&q[(i * 3 + 1) * QS3 + a * 8 + 4];
                const float4 d0 = *(const float4*)&q[(i * 3 + 2) * QS3 + bb * 8];
                const float4 d1 = *(const float4*)&q[(i * 3 + 2) * QS3 + bb * 8 + 4];
                float vv[8];
                vv[0] = c0.x + d0.x; vv[1] = c0.y + d0.y;
                vv[2] = c0.z + d0.z; vv[3] = c0.w + d0.w;
                vv[4] = c1.x + d1.x; vv[5] = c1.y + d1.y;
                vv[6] = c1.z + d1.z; vv[7] = c1.w + d1.w;
                float m = INFINITY;
                #pragma unroll
                for (int cc = 0; cc < 8; ++cc) {
                    const float s = (cc == a || cc == bb) ? INFINITY : (bs + vv[cc]);
                    m = fminf(m, s);
                }
                mn[i] = m;
            }
        }
        #pragma unroll
        for (int s = 1; s <= 32; s <<= 1) {
            #pragma unroll
            for (int i = 0; i < 4; ++i) mn[i] = fminf(mn[i], __shfl_xor(mn[i], s));
        }
        if (lane == 0) {
            const float mx = fmaxf(fmaxf(mn[0], mn[1]), fmaxf(mn[2], mn[3]));
            const float e0 = expf(mn[0] - mx), e1 = expf(mn[1] - mx);
            const float e2 = expf(mn[2] - mx), e3 = expf(mn[3] - mx);
            const float inv = 1.f / (e0 + e1 + e2 + e3);
            *(float4*)(out + (size_t)(b0 + e) * 4) =
                make_float4((e0 + e1) * inv, (e2 + e3) * inv, 0.f, 0.f);
        }

        // ---- LDS reuse guard between elements: wait ONLY on DS ops (reads
        // done -> WAR safe); does NOT drain vmcnt, so elem1 prefetch stays
        // in flight. sched_barrier stops hoisting past it (rule #18).
        if (e == 0) {
            asm volatile("s_waitcnt lgkmcnt(0)" ::: "memory");
            __builtin_amdgcn_sched_barrier(0);
        }
    }
}

extern "C" void kernel_launch(void* const* d_in, const int* in_sizes, int n_in,
                              void* d_out, int out_size, void* d_ws, size_t ws_size,
                              hipStream_t stream) {
    const float* uf = (const float*)d_in[0];   // (4096,8,64)
    const float* bf = (const float*)d_in[1];   // (4096,8,8,64)
    const float* ru = (const float*)d_in[2];   // (4,3,64)
    const float* rb = (const float*)d_in[3];   // (4,3,3,64)
    float* out = (float*)d_out;                // (4096,4)

    const int B = in_sizes[0] / (8 * 64);      // 4096

    rule_prep_kernel<<<16, 256, 0, stream>>>(ru, rb, (__bf16*)d_ws);
    rule_learner_kernel<<<B / 2, 64, 0, stream>>>(uf, bf, (const bf16x8*)d_ws, out);
}

// Round 11
// 20.655 us; speedup vs baseline: 1.5152x; 1.1782x over previous
//
#include <hip/hip_runtime.h>
#include <math.h>

// B=4096, O=8, E=64, I=4, V=3, P=perm(8,3)=336
// unary_feats  (B,8,64)   f32
// binary_feats (B,8,8,64) f32
// rule_unary   (4,3,64)   f32  = [12][64]
// rule_binary  (4,3,3,64) f32  = [36][64]  (rule = i*9 + n*3 + m)
// out          (B,4)      f32  (col0=sel0+sel1, col1=sel2+sel3, col2=col3=0)
//
// v11 = v10 (wave-autonomous, 2 elements/wave, zero block barriers, whole
// grid co-resident) MINUS the prep dispatch: each wave packs the rule
// B-fragments itself from the f32 tensors (16 dwordx4, L1-hot after the
// first block per CU; ~50 cvt VALU ops; amortized over 2 elements).
// Graph = ONE kernel. OOB tile rows/cols handled by address clamping
// (dup loads; garbage C columns are never stored).

typedef __attribute__((ext_vector_type(8))) __bf16 bf16x8;
typedef __attribute__((ext_vector_type(4))) float  f32x4;

#define BMS 68
#define QS3 68

__device__ inline bf16x8 cvt2(const float4 v0, const float4 v1) {
    bf16x8 r;
    r[0] = (__bf16)v0.x; r[1] = (__bf16)v0.y; r[2] = (__bf16)v0.z; r[3] = (__bf16)v0.w;
    r[4] = (__bf16)v1.x; r[5] = (__bf16)v1.y; r[6] = (__bf16)v1.z; r[7] = (__bf16)v1.w;
    return r;
}

__global__ __launch_bounds__(64, 2) void rule_learner_kernel(
    const float* __restrict__ uf,    // (B,8,64)
    const float* __restrict__ bfe,   // (B,8,8,64)
    const float* __restrict__ ru,    // [12][64]
    const float* __restrict__ rb,    // [36][64]
    float* __restrict__ out)         // (B,4)
{
    const int b0    = blockIdx.x * 2;
    const int lane  = threadIdx.x;   // one wave per block
    const int row16 = lane & 15;
    const int kg    = lane >> 4;
    const int kb    = kg * 8;

    __shared__ float bm[36 * BMS];   // 9792 B  [rule][pos]
    __shared__ float um[12 * 12];    // 576 B   [i*3+n][v]
    __shared__ float q [12 * QS3];   // 3264 B  [i*3+t][pair]

    // ---- elem0 feature loads (issue first: coldest) ----
    float4 af[4][4], uA[4];
    {
        const float* base = bfe + (size_t)b0 * 4096;
        #pragma unroll
        for (int t = 0; t < 4; ++t) {
            const float* rp = base + (size_t)(t * 16 + row16) * 64 + kb;
            af[t][0] = *(const float4*)rp;
            af[t][1] = *(const float4*)(rp + 4);
            af[t][2] = *(const float4*)(rp + 32);
            af[t][3] = *(const float4*)(rp + 36);
        }
        const float* up = uf + (size_t)b0 * 512 + (row16 < 8 ? row16 : 7) * 64 + kb;
        uA[0] = *(const float4*)up;
        uA[1] = *(const float4*)(up + 4);
        uA[2] = *(const float4*)(up + 32);
        uA[3] = *(const float4*)(up + 36);
    }

    // ---- rule fragments packed in-wave (L1-hot f32; clamp padding) ----
    // B-frag for 16x16x32 MFMA: col = lane&15, k = h*32 + kg*8 + e
    bf16x8 rbf[6], ruf0, ruf1;
    {
        #pragma unroll
        for (int nt = 0; nt < 3; ++nt) {
            const int rule = nt * 16 + row16;
            const float* rp = rb + (rule < 36 ? rule : 35) * 64 + kb;
            rbf[nt * 2 + 0] = cvt2(*(const float4*)rp,        *(const float4*)(rp + 4));
            rbf[nt * 2 + 1] = cvt2(*(const float4*)(rp + 32), *(const float4*)(rp + 36));
        }
        const float* up = ru + (row16 < 12 ? row16 : 11) * 64 + kb;
        ruf0 = cvt2(*(const float4*)up,        *(const float4*)(up + 4));
        ruf1 = cvt2(*(const float4*)(up + 32), *(const float4*)(up + 36));
    }

    #pragma unroll
    for (int e = 0; e < 2; ++e) {
        // ---- phase 1: MFMA matches into bm/um ----
        #pragma unroll
        for (int t = 0; t < 4; ++t) {
            const bf16x8 a0 = cvt2(af[t][0], af[t][1]);
            const bf16x8 a1 = cvt2(af[t][2], af[t][3]);
            #pragma unroll
            for (int nt = 0; nt < 3; ++nt) {
                f32x4 acc = {0.f, 0.f, 0.f, 0.f};
                acc = __builtin_amdgcn_mfma_f32_16x16x32_bf16(a0, rbf[nt * 2 + 0], acc, 0, 0, 0);
                acc = __builtin_amdgcn_mfma_f32_16x16x32_bf16(a1, rbf[nt * 2 + 1], acc, 0, 0, 0);
                const int rule = nt * 16 + row16;
                if (rule < 36)
                    *(float4*)&bm[rule * BMS + t * 16 + kg * 4] = *(float4*)&acc;
            }
        }
        {
            const bf16x8 ua0 = cvt2(uA[0], uA[1]);
            const bf16x8 ua1 = cvt2(uA[2], uA[3]);
            f32x4 acc = {0.f, 0.f, 0.f, 0.f};
            acc = __builtin_amdgcn_mfma_f32_16x16x32_bf16(ua0, ruf0, acc, 0, 0, 0);
            acc = __builtin_amdgcn_mfma_f32_16x16x32_bf16(ua1, ruf1, acc, 0, 0, 0);
            if (row16 < 12 && kg < 2)
                *(float4*)&um[row16 * 12 + kg * 4] = *(float4*)&acc;
        }

        // ---- issue elem1 loads NOW (latency hides under phases 2-3) ----
        if (e == 0) {
            const float* base = bfe + (size_t)(b0 + 1) * 4096;
            #pragma unroll
            for (int t = 0; t < 4; ++t) {
                const float* rp = base + (size_t)(t * 16 + row16) * 64 + kb;
                af[t][0] = *(const float4*)rp;
                af[t][1] = *(const float4*)(rp + 4);
                af[t][2] = *(const float4*)(rp + 32);
                af[t][3] = *(const float4*)(rp + 36);
            }
            const float* up = uf + (size_t)(b0 + 1) * 512
                            + (row16 < 8 ? row16 : 7) * 64 + kb;
            uA[0] = *(const float4*)up;
            uA[1] = *(const float4*)(up + 4);
            uA[2] = *(const float4*)(up + 32);
            uA[3] = *(const float4*)(up + 36);
        }

        // ---- phase 2: q-tables for all 4 rule-sets (lane = pair (x,y)) ----
        {
            const int x = lane >> 3;
            const int y = lane & 7;
            #pragma unroll
            for (int i = 0; i < 4; ++i) {
                const float* bmi = bm + i * 9 * BMS;
                const float* umi = um + i * 3 * 12;
                const float q01 = umi[x] + umi[12 + y]
                                + bmi[0 * BMS + x * 9] + bmi[4 * BMS + y * 9]
                                + bmi[1 * BMS + x * 8 + y] + bmi[3 * BMS + y * 8 + x];
                const float q02 = umi[24 + y] + bmi[8 * BMS + y * 9]
                                + bmi[2 * BMS + x * 8 + y] + bmi[6 * BMS + y * 8 + x];
                const float q12 = bmi[5 * BMS + x * 8 + y] + bmi[7 * BMS + y * 8 + x];
                q[(i * 3 + 0) * QS3 + lane] = q01;
                q[(i * 3 + 1) * QS3 + lane] = q02;
                q[(i * 3 + 2) * QS3 + lane] = q12;
            }
        }

        // ---- phase 3: lane = ordered pair (a,bb), sweep cc for all 4 i ----
        float mn[4] = {INFINITY, INFINITY, INFINITY, INFINITY};
        if (lane < 56) {
            const int a  = lane / 7;
            const int o  = lane - a * 7;
            const int bb = o + (o >= a);
            #pragma unroll
            for (int i = 0; i < 4; ++i) {
                const float bs  = q[(i * 3 + 0) * QS3 + a * 8 + bb];
                const float4 c0 = *(const float4*)&q[(i * 3 + 1) * QS3 + a * 8];
                const float4 c1 = *(const float4*)&q[(i * 3 + 1) * QS3 + a * 8 + 4];
                const float4 d0 = *(const float4*)&q[(i * 3 + 2) * QS3 + bb * 8];
                const float4 d1 = *(const float4*)&q[(i * 3 + 2) * QS3 + bb * 8 + 4];
                float vv[8];
                vv[0] = c0.x + d0.x; vv[1] = c0.y + d0.y;
                vv[2] = c0.z + d0.z; vv[3] = c0.w + d0.w;
                vv[4] = c1.x + d1.x; vv[5] = c1.y + d1.y;
                vv[6] = c1.z + d1.z; vv[7] = c1.w + d1.w;
                float m = INFINITY;
                #pragma unroll
                for (int cc = 0; cc < 8; ++cc) {
                    const float s = (cc == a || cc == bb) ? INFINITY : (bs + vv[cc]);
                    m = fminf(m, s);
                }
                mn[i] = m;
            }
        }
        #pragma unroll
        for (int s = 1; s <= 32; s <<= 1) {
            #pragma unroll
            for (int i = 0; i < 4; ++i) mn[i] = fminf(mn[i], __shfl_xor(mn[i], s));
        }
        if (lane == 0) {
            const float mx = fmaxf(fmaxf(mn[0], mn[1]), fmaxf(mn[2], mn[3]));
            const float e0 = expf(mn[0] - mx), e1 = expf(mn[1] - mx);
            const float e2 = expf(mn[2] - mx), e3 = expf(mn[3] - mx);
            const float inv = 1.f / (e0 + e1 + e2 + e3);
            *(float4*)(out + (size_t)(b0 + e) * 4) =
                make_float4((e0 + e1) * inv, (e2 + e3) * inv, 0.f, 0.f);
        }

        // ---- LDS reuse guard between elements: wait ONLY on DS ops (reads
        // done -> WAR safe); does NOT drain vmcnt, so elem1 prefetch stays
        // in flight. sched_barrier stops hoisting past it (rule #18).
        if (e == 0) {
            asm volatile("s_waitcnt lgkmcnt(0)" ::: "memory");
            __builtin_amdgcn_sched_barrier(0);
        }
    }
}

extern "C" void kernel_launch(void* const* d_in, const int* in_sizes, int n_in,
                              void* d_out, int out_size, void* d_ws, size_t ws_size,
                              hipStream_t stream) {
    const float* uf = (const float*)d_in[0];   // (4096,8,64)
    const float* bf = (const float*)d_in[1];   // (4096,8,8,64)
    const float* ru = (const float*)d_in[2];   // (4,3,64)
    const float* rb = (const float*)d_in[3];   // (4,3,3,64)
    float* out = (float*)d_out;                // (4096,4)

    const int B = in_sizes[0] / (8 * 64);      // 4096
    rule_learner_kernel<<<B / 2, 64, 0, stream>>>(uf, bf, ru, rb, out);
}